// Round 13
// baseline (205.114 us; speedup 1.0000x reference)
//
#include <hip/hip_runtime.h>
#include <math.h>

#define BB   64
#define NN   1024
#define FIN  16
#define DIM  64
#define KK   20
#define EPSV 1e-5f
#define SLOPE 0.2f
#define BN_COUNT (BB*NN)
#define RD 32   // acc1 replicas
#define RF 16   // acc2 replicas

// ---------------- k1: keys GEMM + prep (u_i/u_j, e_i/e_j, acc zero) ------
__global__ __launch_bounds__(256)
void k1(const float* __restrict__ emb, const float* __restrict__ lin_w,
        const float* __restrict__ att_i, const float* __restrict__ att_j,
        const float* __restrict__ att_em_i, const float* __restrict__ att_em_j,
        float* __restrict__ keys, float* __restrict__ prep,
        float* __restrict__ accz){
  __shared__ float a_lds[64*68];
  __shared__ float bT[64*68];
  __shared__ float rs[64];
  int p = blockIdx.x, t = threadIdx.x;
  int it = p >> 4, jt = p & 15;
  if (p == 0){
    for (int u = t; u < (RD+RF)*128; u += 256) accz[u] = 0.f;
    if (t < 16){
      float ui = 0.f, uj = 0.f;
      #pragma unroll 1
      for (int d = 0; d < 64; d++){
        float w = lin_w[d*16 + t];
        ui += w * att_i[d];
        uj += w * att_j[d];
      }
      prep[t] = ui;        // u_i[16]
      prep[16 + t] = uj;   // u_j[16]
    }
  }
  const float4* e4 = (const float4*)emb;
  #pragma unroll
  for (int u0 = 0; u0 < 1024; u0 += 256){
    int u = u0 + t;
    int r = u >> 4, q = u & 15;
    float4 v = e4[(it*64 + r)*16 + q];
    *(float4*)&a_lds[r*68 + q*4] = v;
  }
  #pragma unroll
  for (int u0 = 0; u0 < 1024; u0 += 256){
    int u = u0 + t;
    int r = u >> 4, q = u & 15;
    float4 v = e4[(jt*64 + r)*16 + q];
    int d0 = q*4;
    bT[(d0+0)*68 + r] = v.x;
    bT[(d0+1)*68 + r] = v.y;
    bT[(d0+2)*68 + r] = v.z;
    bT[(d0+3)*68 + r] = v.w;
  }
  __syncthreads();
  if (t < 64){
    float s = 0.f;
    #pragma unroll
    for (int d = 0; d < 64; d++){ float x = bT[d*68 + t]; s += x*x; }
    rs[t] = rsqrtf(s);
  }
  if (it == 0 && t >= 128 && t < 192){
    int r = t - 128;
    float ei = 0.f;
    #pragma unroll 1
    for (int d = 0; d < 64; d++) ei += bT[d*68 + r] * att_em_i[d];
    prep[32 + jt*64 + r] = ei;               // e_i[1024]
  }
  if (it == 0 && t >= 192){
    int r = t - 192;
    float ej = 0.f;
    #pragma unroll 1
    for (int d = 0; d < 64; d++) ej += bT[d*68 + r] * att_em_j[d];
    prep[32 + 1024 + jt*64 + r] = ej;        // e_j[1024]
  }
  __syncthreads();
  int tx = t & 15, ty = t >> 4;
  float4 acc[4];
  #pragma unroll
  for (int r = 0; r < 4; r++) acc[r] = (float4){0.f,0.f,0.f,0.f};
  #pragma unroll
  for (int d4 = 0; d4 < 16; d4++){
    float4 av[4], bv[4];
    #pragma unroll
    for (int r = 0; r < 4; r++) av[r] = *(const float4*)&a_lds[(ty*4+r)*68 + d4*4];
    #pragma unroll
    for (int dd = 0; dd < 4; dd++) bv[dd] = *(const float4*)&bT[(d4*4+dd)*68 + tx*4];
    #pragma unroll
    for (int r = 0; r < 4; r++){
      acc[r].x += av[r].x*bv[0].x; acc[r].y += av[r].x*bv[0].y;
      acc[r].z += av[r].x*bv[0].z; acc[r].w += av[r].x*bv[0].w;
      acc[r].x += av[r].y*bv[1].x; acc[r].y += av[r].y*bv[1].y;
      acc[r].z += av[r].y*bv[1].z; acc[r].w += av[r].y*bv[1].w;
      acc[r].x += av[r].z*bv[2].x; acc[r].y += av[r].z*bv[2].y;
      acc[r].z += av[r].z*bv[2].z; acc[r].w += av[r].z*bv[2].w;
      acc[r].x += av[r].w*bv[3].x; acc[r].y += av[r].w*bv[3].y;
      acc[r].z += av[r].w*bv[3].z; acc[r].w += av[r].w*bv[3].w;
    }
  }
  float4 rs4 = {rs[tx*4+0], rs[tx*4+1], rs[tx*4+2], rs[tx*4+3]};
  float4* k4 = (float4*)keys;
  #pragma unroll
  for (int r = 0; r < 4; r++){
    int gi = it*64 + ty*4 + r;
    float4 o = {acc[r].x*rs4.x, acc[r].y*rs4.y, acc[r].z*rs4.z, acc[r].w*rs4.w};
    k4[gi*256 + jt*16 + tx] = o;
  }
}

// ------- k2: fused kS (blocks 0..127) + kC (blocks 128..4223) ------------
__global__ __launch_bounds__(256)
void k2(const float* __restrict__ keys, const float* __restrict__ data,
        const float* __restrict__ lin_w, const float* __restrict__ prep,
        int* __restrict__ topk, float* __restrict__ h,
        float* __restrict__ s_i, float* __restrict__ s_j){
  __shared__ float smem[FIN*DIM + 16*FIN];
  int p = blockIdx.x, t = threadIdx.x;
  int wave = t >> 6, lane = t & 63;
  if (p < 128){
    int i0 = p*8 + wave*2;
    const float4* k4 = (const float4*)keys;
    float cA[16], cB[16];
    #pragma unroll
    for (int q = 0; q < 4; q++){
      float4 vA = k4[(i0+0)*256 + q*64 + lane];
      float4 vB = k4[(i0+1)*256 + q*64 + lane];
      cA[q*4+0]=vA.x; cA[q*4+1]=vA.y; cA[q*4+2]=vA.z; cA[q*4+3]=vA.w;
      cB[q*4+0]=vB.x; cB[q*4+1]=vB.y; cB[q*4+2]=vB.z; cB[q*4+3]=vB.w;
    }
    float lvA = cA[0]; int liA = 0;
    float lvB = cB[0]; int liB = 0;
    #pragma unroll
    for (int m = 1; m < 16; m++){
      if (cA[m] > lvA){ lvA = cA[m]; liA = m; }
      if (cB[m] > lvB){ lvB = cB[m]; liB = m; }
    }
    #pragma unroll 1
    for (int k = 0; k < KK; k++){
      float bvA = lvA; int bjA = ((liA>>2)<<8) + (lane<<2) + (liA&3);
      float bvB = lvB; int bjB = ((liB>>2)<<8) + (lane<<2) + (liB&3);
      #pragma unroll
      for (int msk = 32; msk > 0; msk >>= 1){
        float pvA = __shfl_xor(bvA, msk, 64); int pjA = __shfl_xor(bjA, msk, 64);
        float pvB = __shfl_xor(bvB, msk, 64); int pjB = __shfl_xor(bjB, msk, 64);
        if (pvA > bvA || (pvA == bvA && pjA < bjA)){ bvA = pvA; bjA = pjA; }
        if (pvB > bvB || (pvB == bvB && pjB < bjB)){ bvB = pvB; bjB = pjB; }
      }
      if (lane == 0){
        topk[(i0+0)*KK + k] = bjA;
        topk[(i0+1)*KK + k] = bjB;
      }
      if (((bjA>>2)&63) == lane){
        cA[((bjA>>8)<<2) + (bjA&3)] = -1e30f;
        lvA = cA[0]; liA = 0;
        #pragma unroll
        for (int m = 1; m < 16; m++) if (cA[m] > lvA){ lvA = cA[m]; liA = m; }
      }
      if (((bjB>>2)&63) == lane){
        cB[((bjB>>8)<<2) + (bjB&3)] = -1e30f;
        lvB = cB[0]; liB = 0;
        #pragma unroll
        for (int m = 1; m < 16; m++) if (cB[m] > lvB){ lvB = cB[m]; liB = m; }
      }
    }
  } else {
    float* lw = smem;
    float* sd = smem + FIN*DIM;
    for (int u = t; u < FIN*DIM; u += 256){
      int d = u >> 4, f = u & 15;
      lw[f*DIM + d] = lin_w[u];
    }
    int r0 = (p - 128)*16;
    sd[t] = data[r0*FIN + t];
    __syncthreads();
    #pragma unroll
    for (int q = 0; q < 4; q++){
      int row = wave*4 + q;
      int r = r0 + row;
      float acc = 0.f;
      #pragma unroll
      for (int f4 = 0; f4 < 4; f4++){
        float4 d4 = ((const float4*)(sd + row*FIN))[f4];
        acc += d4.x * lw[(f4*4+0)*DIM + lane];
        acc += d4.y * lw[(f4*4+1)*DIM + lane];
        acc += d4.z * lw[(f4*4+2)*DIM + lane];
        acc += d4.w * lw[(f4*4+3)*DIM + lane];
      }
      h[r*DIM + lane] = acc;
    }
    if (t < 32){
      int row = t & 15;
      int r = r0 + row;
      int n = r & (NN-1);
      const float* uvec = prep + ((t < 16) ? 0 : 16);
      const float* evec = prep + 32 + ((t < 16) ? 0 : 1024);
      float s = 0.f;
      #pragma unroll
      for (int f = 0; f < FIN; f++) s += sd[row*FIN + f] * uvec[f];
      s += evec[n];
      if (t < 16) s_i[r] = s; else s_j[r] = s;
    }
  }
}

// ------- kA2: thread-per-row softmax -> alpha[r][20] ---------------------
__global__ __launch_bounds__(256)
void kA2(const float* __restrict__ s_i, const float* __restrict__ s_j,
         const int* __restrict__ topk, float* __restrict__ alpha){
  int r = blockIdx.x*256 + threadIdx.x;
  int b = r >> 10, n = r & (NN-1);
  const int4* tk4 = (const int4*)(topk + n*KK);
  int idx[KK];
  #pragma unroll
  for (int q = 0; q < 5; q++){
    int4 v = tk4[q];
    idx[q*4+0]=v.x; idx[q*4+1]=v.y; idx[q*4+2]=v.z; idx[q*4+3]=v.w;
  }
  float siv = s_i[r];
  const float* sjb = s_j + b*NN;
  float xv[KK];
  #pragma unroll
  for (int k = 0; k < KK; k++){
    float x = siv + sjb[idx[k]];
    xv[k] = (x > 0.f) ? x : SLOPE * x;
  }
  float m = xv[0];
  #pragma unroll
  for (int k = 1; k < KK; k++) m = fmaxf(m, xv[k]);
  float ssum = 0.f;
  #pragma unroll
  for (int k = 0; k < KK; k++){ xv[k] = __expf(xv[k] - m); ssum += xv[k]; }
  float rinv = 1.f / ssum;
  float4* a4 = (float4*)(alpha + (size_t)r*KK);
  #pragma unroll
  for (int q = 0; q < 5; q++){
    float4 v = {xv[q*4+0]*rinv, xv[q*4+1]*rinv, xv[q*4+2]*rinv, xv[q*4+3]*rinv};
    a4[q] = v;
  }
}

// ------- kD: paired-row dwordx2 gather-FMA + BN1 stats -------------------
// One wave = 2 rows per step (lanes 0..31 row A, 32..63 row B), 2 steps
// -> 4 rows/wave, 16 rows/block. 20 dwordx2 gathers + 1 dwordx2 store per
// row-pair (half the VMEM instructions of dword/row). XCD-swizzled.
__global__ __launch_bounds__(256, 4)
void kD(const float* __restrict__ h, const float* __restrict__ alpha,
        const int* __restrict__ topk, const float* __restrict__ gnn_bias,
        float* __restrict__ outp, float* __restrict__ acc){
  __shared__ float sm[128];
  int t = threadIdx.x, wave = t >> 6, lane = t & 63;
  if (t < 128) sm[t] = 0.f;
  __syncthreads();
  int p = blockIdx.x;
  int xcd = p & 7, slot = p >> 3;
  int b = xcd + 8*(slot >> 6);               // 8 batches/XCD -> 2MB L2 set
  int chunk = slot & 63;                     // 16 rows per block
  const float* hb = h + (size_t)b * NN * DIM;
  int rowsel = lane >> 5, ch = lane & 31;    // ch covers 2 channels
  float2 gb2 = *(const float2*)(gnn_bias + ch*2);
  float ps0 = 0.f, ps1 = 0.f, pq0 = 0.f, pq1 = 0.f;
  #pragma unroll 1
  for (int it = 0; it < 2; it++){            // 2 pair-steps x 2 rows = 4 rows/wave
    int nuA = __builtin_amdgcn_readfirstlane(chunk*16 + wave*4 + it*2 + 0);
    int nuB = nuA + 1;
    const float* arowA = alpha + ((size_t)b*NN + nuA)*KK;
    const float* arowB = alpha + ((size_t)b*NN + nuB)*KK;
    int idxs[KK];
    float as[KK];
    #pragma unroll
    for (int k = 0; k < KK; k++){
      int iA = __builtin_amdgcn_readfirstlane(topk[nuA*KK + k]);
      int iB = __builtin_amdgcn_readfirstlane(topk[nuB*KK + k]);
      idxs[k] = rowsel ? iB : iA;
      as[k]   = rowsel ? arowB[k] : arowA[k];
    }
    float2 g[KK];
    #pragma unroll
    for (int k = 0; k < KK; k++)
      g[k] = *(const float2*)(hb + idxs[k]*DIM + ch*2);
    float2 o = {gb2.x, gb2.y};
    #pragma unroll
    for (int k = 0; k < KK; k++){
      o.x += as[k] * g[k].x;
      o.y += as[k] * g[k].y;
    }
    int nu = rowsel ? nuB : nuA;
    *(float2*)(outp + ((size_t)b*NN + nu)*DIM + ch*2) = o;
    ps0 += o.x; pq0 += o.x*o.x;
    ps1 += o.y; pq1 += o.y*o.y;
  }
  atomicAdd(&sm[ch*2+0], ps0);
  atomicAdd(&sm[ch*2+1], ps1);
  atomicAdd(&sm[64+ch*2+0], pq0);
  atomicAdd(&sm[64+ch*2+1], pq1);
  __syncthreads();
  float* accr = acc + (p & (RD-1))*128;
  if (t < 128) atomicAdd(&accr[t], sm[t]);
}

// ------- kF: BN1 finalize + BN2 stats; XCD-aligned with kD's writes ------
__global__ void kF(const float* __restrict__ outp, const float* __restrict__ emb,
                   const float* __restrict__ acc, const float* __restrict__ bn1_g,
                   const float* __restrict__ bn1_b, float* __restrict__ acc2){
  __shared__ float prm[128];
  __shared__ float chs[DIM], chq[DIM];
  int t = threadIdx.x;
  if (t < DIM){ chs[t] = 0.f; chq[t] = 0.f; }
  if (t < 64){
    float smv = 0.f, sqv = 0.f;
    #pragma unroll
    for (int rp = 0; rp < RD; rp++){
      smv += acc[rp*128 + t];
      sqv += acc[rp*128 + 64 + t];
    }
    float mean = smv * (1.f / BN_COUNT);
    float var  = sqv * (1.f / BN_COUNT) - mean*mean;
    float sc = bn1_g[t] * rsqrtf(var + EPSV);
    prm[t]    = sc;
    prm[64+t] = bn1_b[t] - mean*sc;
  }
  __syncthreads();
  int cbase = (t*4) & 63;
  float4 sc = *(const float4*)(prm + cbase);
  float4 bs = *(const float4*)(prm + 64 + cbase);
  float s0=0,s1=0,s2=0,s3=0,q0=0,q1=0,q2=0,q3=0;
  const float4* op4 = (const float4*)outp;
  const float4* em4 = (const float4*)emb;
  int p = blockIdx.x;
  int xcd = p & 7, slot = p >> 3;
  int b = xcd + 8*(slot & 7);
  int chunk = slot >> 3;                 // 0..31
  int e0 = b*(NN*DIM/4) + chunk*512;
  #pragma unroll
  for (int ii = 0; ii < 2; ii++){
    int e = e0 + ii*256 + t;
    float4 x = op4[e];
    float4 em = em4[e & (NN*DIM/4 - 1)];
    float4 y;
    y.x = fmaxf(x.x*sc.x + bs.x, 0.f) * em.x;
    y.y = fmaxf(x.y*sc.y + bs.y, 0.f) * em.y;
    y.z = fmaxf(x.z*sc.z + bs.z, 0.f) * em.z;
    y.w = fmaxf(x.w*sc.w + bs.w, 0.f) * em.w;
    s0 += y.x; q0 += y.x*y.x;
    s1 += y.y; q1 += y.y*y.y;
    s2 += y.z; q2 += y.z*y.z;
    s3 += y.w; q3 += y.w*y.w;
  }
  atomicAdd(&chs[cbase+0], s0); atomicAdd(&chq[cbase+0], q0);
  atomicAdd(&chs[cbase+1], s1); atomicAdd(&chq[cbase+1], q1);
  atomicAdd(&chs[cbase+2], s2); atomicAdd(&chq[cbase+2], q2);
  atomicAdd(&chs[cbase+3], s3); atomicAdd(&chq[cbase+3], q3);
  __syncthreads();
  float* acc2r = acc2 + (blockIdx.x & (RF-1))*128;
  if (t < 128) atomicAdd(&acc2r[t], (t < 64) ? chs[t] : chq[t-64]);
}

// ------- kH: finalize BN1+BN2, recompute rep inline, dot; XCD-aligned ----
__global__ void kH(const float* __restrict__ outp, const float* __restrict__ emb,
                   const float* __restrict__ acc, const float* __restrict__ acc2,
                   const float* __restrict__ bn1_g, const float* __restrict__ bn1_b,
                   const float* __restrict__ bn2_g, const float* __restrict__ bn2_b,
                   const float* __restrict__ out_w, const float* __restrict__ out_b,
                   float* __restrict__ out){
  __shared__ float prm[256];
  int t = threadIdx.x, wave = t >> 6, lane = t & 63;
  if (t < 64){
    float smv = 0.f, sqv = 0.f;
    #pragma unroll
    for (int rp = 0; rp < RD; rp++){
      smv += acc[rp*128 + t];
      sqv += acc[rp*128 + 64 + t];
    }
    float mean = smv * (1.f / BN_COUNT);
    float var  = sqv * (1.f / BN_COUNT) - mean*mean;
    float sc = bn1_g[t] * rsqrtf(var + EPSV);
    prm[t]    = sc;
    prm[64+t] = bn1_b[t] - mean*sc;
  } else if (t < 128) {
    int d = t - 64;
    float smv = 0.f, sqv = 0.f;
    #pragma unroll
    for (int rp = 0; rp < RF; rp++){
      smv += acc2[rp*128 + d];
      sqv += acc2[rp*128 + 64 + d];
    }
    float mean = smv * (1.f / BN_COUNT);
    float var  = sqv * (1.f / BN_COUNT) - mean*mean;
    float sc = bn2_g[d] * rsqrtf(var + EPSV);
    prm[128+d] = sc;
    prm[192+d] = bn2_b[d] - mean*sc;
  }
  __syncthreads();
  int c16 = lane & 15, rsub = lane >> 4;
  int cb = c16*4;
  float4 sc1 = *(const float4*)(prm + cb);
  float4 bs1 = *(const float4*)(prm + 64 + cb);
  float4 sc2 = *(const float4*)(prm + 128 + cb);
  float4 bs2 = *(const float4*)(prm + 192 + cb);
  float4 w4 = *(const float4*)(out_w + cb);
  float ob = out_b[0];
  int p = blockIdx.x;
  int xcd = p & 7, slot = p >> 3;
  int b = xcd + 8*(slot >> 4);
  int chunk = slot & 15;                  // 64 rows per block
  int rbase = b*NN + chunk*64 + wave*16;
  #pragma unroll 1
  for (int i = 0; i < 16; i += 4){
    int r = rbase + i + rsub;
    int n = r & (NN-1);
    float4 x  = *(const float4*)(outp + (size_t)r*DIM + cb);
    float4 em = *(const float4*)(emb + n*DIM + cb);
    float4 y;
    y.x = fmaxf(x.x*sc1.x + bs1.x, 0.f) * em.x;
    y.y = fmaxf(x.y*sc1.y + bs1.y, 0.f) * em.y;
    y.z = fmaxf(x.z*sc1.z + bs1.z, 0.f) * em.z;
    y.w = fmaxf(x.w*sc1.w + bs1.w, 0.f) * em.w;
    float pr = fmaxf(y.x*sc2.x + bs2.x, 0.f) * w4.x
             + fmaxf(y.y*sc2.y + bs2.y, 0.f) * w4.y
             + fmaxf(y.z*sc2.z + bs2.z, 0.f) * w4.z
             + fmaxf(y.w*sc2.w + bs2.w, 0.f) * w4.w;
    pr += __shfl_xor(pr, 1, 64); pr += __shfl_xor(pr, 2, 64);
    pr += __shfl_xor(pr, 4, 64); pr += __shfl_xor(pr, 8, 64);
    if (c16 == 0) out[r] = pr + ob;
  }
}

extern "C" void kernel_launch(void* const* d_in, const int* in_sizes, int n_in,
                              void* d_out, int out_size, void* d_ws, size_t ws_size,
                              hipStream_t stream) {
  const float* data     = (const float*)d_in[0];
  const float* emb      = (const float*)d_in[2];
  const float* lin_w    = (const float*)d_in[3];
  const float* att_i    = (const float*)d_in[4];
  const float* att_j    = (const float*)d_in[5];
  const float* att_em_i = (const float*)d_in[6];
  const float* att_em_j = (const float*)d_in[7];
  const float* gnn_bias = (const float*)d_in[8];
  const float* bn1_g    = (const float*)d_in[9];
  const float* bn1_b    = (const float*)d_in[10];
  const float* bn2_g    = (const float*)d_in[11];
  const float* bn2_b    = (const float*)d_in[12];
  const float* out_w    = (const float*)d_in[13];
  const float* out_b    = (const float*)d_in[14];
  float* out = (float*)d_out;

  float* ws   = (float*)d_ws;
  float* h    = ws;                        // 4194304 floats
  float* outp = ws + 4194304;              // 4194304 (keys aliases first 1M)
  float* s_i  = ws + 8388608;              // 65536
  float* s_j  = s_i + 65536;               // 65536
  int*   topk = (int*)(s_j + 65536);       // 20480 ints
  float* acc1 = (float*)(topk + NN*KK);    // RD*128
  float* acc2 = acc1 + RD*128;             // RF*128
  float* prep = acc2 + RF*128;             // 32 + 2048
  float* alpha= prep + 32 + 2048;          // 65536*20 floats
  float* keys = outp;                      // dead before kD writes outp

  k1<<<256, 256, 0, stream>>>(emb, lin_w, att_i, att_j, att_em_i, att_em_j,
                              keys, prep, acc1);
  k2<<<128 + (BB*NN)/16, 256, 0, stream>>>(keys, data, lin_w, prep,
                                           topk, h, s_i, s_j);
  kA2<<<(BB*NN)/256, 256, 0, stream>>>(s_i, s_j, topk, alpha);
  kD<<<(BB*NN)/16, 256, 0, stream>>>(h, alpha, topk, gnn_bias, outp, acc1);
  kF<<<2048, 256, 0, stream>>>(outp, emb, acc1, bn1_g, bn1_b, acc2);
  kH<<<NN, 256, 0, stream>>>(outp, emb, acc1, acc2, bn1_g, bn1_b,
                             bn2_g, bn2_b, out_w, out_b, out);
}

// Round 14
// 188.164 us; speedup vs baseline: 1.0901x; 1.0901x over previous
//
#include <hip/hip_runtime.h>
#include <math.h>

#define BB   64
#define NN   1024
#define FIN  16
#define DIM  64
#define KK   20
#define EPSV 1e-5f
#define SLOPE 0.2f
#define BN_COUNT (BB*NN)
#define RD 32   // acc1 replicas (kD: 4096 blocks -> 128 chains/address)
#define RF 16   // acc2 replicas (kF: 2048 blocks -> 128 chains/address)

// ---------------- k1: keys GEMM + prep (u_i/u_j, e_i/e_j, acc zero) ------
__global__ __launch_bounds__(256)
void k1(const float* __restrict__ emb, const float* __restrict__ lin_w,
        const float* __restrict__ att_i, const float* __restrict__ att_j,
        const float* __restrict__ att_em_i, const float* __restrict__ att_em_j,
        float* __restrict__ keys, float* __restrict__ prep,
        float* __restrict__ accz){
  __shared__ float a_lds[64*68];
  __shared__ float bT[64*68];
  __shared__ float rs[64];
  int p = blockIdx.x, t = threadIdx.x;
  int it = p >> 4, jt = p & 15;
  if (p == 0){
    for (int u = t; u < (RD+RF)*128; u += 256) accz[u] = 0.f;
    if (t < 16){
      float ui = 0.f, uj = 0.f;
      #pragma unroll 1
      for (int d = 0; d < 64; d++){
        float w = lin_w[d*16 + t];
        ui += w * att_i[d];
        uj += w * att_j[d];
      }
      prep[t] = ui;        // u_i[16]
      prep[16 + t] = uj;   // u_j[16]
    }
  }
  const float4* e4 = (const float4*)emb;
  #pragma unroll
  for (int u0 = 0; u0 < 1024; u0 += 256){
    int u = u0 + t;
    int r = u >> 4, q = u & 15;
    float4 v = e4[(it*64 + r)*16 + q];
    *(float4*)&a_lds[r*68 + q*4] = v;
  }
  #pragma unroll
  for (int u0 = 0; u0 < 1024; u0 += 256){
    int u = u0 + t;
    int r = u >> 4, q = u & 15;
    float4 v = e4[(jt*64 + r)*16 + q];
    int d0 = q*4;
    bT[(d0+0)*68 + r] = v.x;
    bT[(d0+1)*68 + r] = v.y;
    bT[(d0+2)*68 + r] = v.z;
    bT[(d0+3)*68 + r] = v.w;
  }
  __syncthreads();
  if (t < 64){
    float s = 0.f;
    #pragma unroll
    for (int d = 0; d < 64; d++){ float x = bT[d*68 + t]; s += x*x; }
    rs[t] = rsqrtf(s);
  }
  if (it == 0 && t >= 128 && t < 192){
    int r = t - 128;
    float ei = 0.f;
    #pragma unroll 1
    for (int d = 0; d < 64; d++) ei += bT[d*68 + r] * att_em_i[d];
    prep[32 + jt*64 + r] = ei;               // e_i[1024]
  }
  if (it == 0 && t >= 192){
    int r = t - 192;
    float ej = 0.f;
    #pragma unroll 1
    for (int d = 0; d < 64; d++) ej += bT[d*68 + r] * att_em_j[d];
    prep[32 + 1024 + jt*64 + r] = ej;        // e_j[1024]
  }
  __syncthreads();
  int tx = t & 15, ty = t >> 4;
  float4 acc[4];
  #pragma unroll
  for (int r = 0; r < 4; r++) acc[r] = (float4){0.f,0.f,0.f,0.f};
  #pragma unroll
  for (int d4 = 0; d4 < 16; d4++){
    float4 av[4], bv[4];
    #pragma unroll
    for (int r = 0; r < 4; r++) av[r] = *(const float4*)&a_lds[(ty*4+r)*68 + d4*4];
    #pragma unroll
    for (int dd = 0; dd < 4; dd++) bv[dd] = *(const float4*)&bT[(d4*4+dd)*68 + tx*4];
    #pragma unroll
    for (int r = 0; r < 4; r++){
      acc[r].x += av[r].x*bv[0].x; acc[r].y += av[r].x*bv[0].y;
      acc[r].z += av[r].x*bv[0].z; acc[r].w += av[r].x*bv[0].w;
      acc[r].x += av[r].y*bv[1].x; acc[r].y += av[r].y*bv[1].y;
      acc[r].z += av[r].y*bv[1].z; acc[r].w += av[r].y*bv[1].w;
      acc[r].x += av[r].z*bv[2].x; acc[r].y += av[r].z*bv[2].y;
      acc[r].z += av[r].z*bv[2].z; acc[r].w += av[r].z*bv[2].w;
      acc[r].x += av[r].w*bv[3].x; acc[r].y += av[r].w*bv[3].y;
      acc[r].z += av[r].w*bv[3].z; acc[r].w += av[r].w*bv[3].w;
    }
  }
  float4 rs4 = {rs[tx*4+0], rs[tx*4+1], rs[tx*4+2], rs[tx*4+3]};
  float4* k4 = (float4*)keys;
  #pragma unroll
  for (int r = 0; r < 4; r++){
    int gi = it*64 + ty*4 + r;
    float4 o = {acc[r].x*rs4.x, acc[r].y*rs4.y, acc[r].z*rs4.z, acc[r].w*rs4.w};
    k4[gi*256 + jt*16 + tx] = o;
  }
}

// ------- k2: fused kS (blocks 0..127) + kC (blocks 128..4223) ------------
__global__ __launch_bounds__(256)
void k2(const float* __restrict__ keys, const float* __restrict__ data,
        const float* __restrict__ lin_w, const float* __restrict__ prep,
        int* __restrict__ topk, float* __restrict__ h,
        float* __restrict__ s_i, float* __restrict__ s_j){
  __shared__ float smem[FIN*DIM + 16*FIN];
  int p = blockIdx.x, t = threadIdx.x;
  int wave = t >> 6, lane = t & 63;
  if (p < 128){
    int i0 = p*8 + wave*2;
    const float4* k4 = (const float4*)keys;
    float cA[16], cB[16];
    #pragma unroll
    for (int q = 0; q < 4; q++){
      float4 vA = k4[(i0+0)*256 + q*64 + lane];
      float4 vB = k4[(i0+1)*256 + q*64 + lane];
      cA[q*4+0]=vA.x; cA[q*4+1]=vA.y; cA[q*4+2]=vA.z; cA[q*4+3]=vA.w;
      cB[q*4+0]=vB.x; cB[q*4+1]=vB.y; cB[q*4+2]=vB.z; cB[q*4+3]=vB.w;
    }
    float lvA = cA[0]; int liA = 0;
    float lvB = cB[0]; int liB = 0;
    #pragma unroll
    for (int m = 1; m < 16; m++){
      if (cA[m] > lvA){ lvA = cA[m]; liA = m; }
      if (cB[m] > lvB){ lvB = cB[m]; liB = m; }
    }
    #pragma unroll 1
    for (int k = 0; k < KK; k++){
      float bvA = lvA; int bjA = ((liA>>2)<<8) + (lane<<2) + (liA&3);
      float bvB = lvB; int bjB = ((liB>>2)<<8) + (lane<<2) + (liB&3);
      #pragma unroll
      for (int msk = 32; msk > 0; msk >>= 1){
        float pvA = __shfl_xor(bvA, msk, 64); int pjA = __shfl_xor(bjA, msk, 64);
        float pvB = __shfl_xor(bvB, msk, 64); int pjB = __shfl_xor(bjB, msk, 64);
        if (pvA > bvA || (pvA == bvA && pjA < bjA)){ bvA = pvA; bjA = pjA; }
        if (pvB > bvB || (pvB == bvB && pjB < bjB)){ bvB = pvB; bjB = pjB; }
      }
      if (lane == 0){
        topk[(i0+0)*KK + k] = bjA;
        topk[(i0+1)*KK + k] = bjB;
      }
      if (((bjA>>2)&63) == lane){
        cA[((bjA>>8)<<2) + (bjA&3)] = -1e30f;
        lvA = cA[0]; liA = 0;
        #pragma unroll
        for (int m = 1; m < 16; m++) if (cA[m] > lvA){ lvA = cA[m]; liA = m; }
      }
      if (((bjB>>2)&63) == lane){
        cB[((bjB>>8)<<2) + (bjB&3)] = -1e30f;
        lvB = cB[0]; liB = 0;
        #pragma unroll
        for (int m = 1; m < 16; m++) if (cB[m] > lvB){ lvB = cB[m]; liB = m; }
      }
    }
  } else {
    float* lw = smem;
    float* sd = smem + FIN*DIM;
    for (int u = t; u < FIN*DIM; u += 256){
      int d = u >> 4, f = u & 15;
      lw[f*DIM + d] = lin_w[u];
    }
    int r0 = (p - 128)*16;
    sd[t] = data[r0*FIN + t];
    __syncthreads();
    #pragma unroll
    for (int q = 0; q < 4; q++){
      int row = wave*4 + q;
      int r = r0 + row;
      float acc = 0.f;
      #pragma unroll
      for (int f4 = 0; f4 < 4; f4++){
        float4 d4 = ((const float4*)(sd + row*FIN))[f4];
        acc += d4.x * lw[(f4*4+0)*DIM + lane];
        acc += d4.y * lw[(f4*4+1)*DIM + lane];
        acc += d4.z * lw[(f4*4+2)*DIM + lane];
        acc += d4.w * lw[(f4*4+3)*DIM + lane];
      }
      h[r*DIM + lane] = acc;
    }
    if (t < 32){
      int row = t & 15;
      int r = r0 + row;
      int n = r & (NN-1);
      const float* uvec = prep + ((t < 16) ? 0 : 16);
      const float* evec = prep + 32 + ((t < 16) ? 0 : 1024);
      float s = 0.f;
      #pragma unroll
      for (int f = 0; f < FIN; f++) s += sd[row*FIN + f] * uvec[f];
      s += evec[n];
      if (t < 16) s_i[r] = s; else s_j[r] = s;
    }
  }
}

// ------- kA2: thread-per-row softmax -> alpha[r][20] ---------------------
__global__ __launch_bounds__(256)
void kA2(const float* __restrict__ s_i, const float* __restrict__ s_j,
         const int* __restrict__ topk, float* __restrict__ alpha){
  int r = blockIdx.x*256 + threadIdx.x;
  int b = r >> 10, n = r & (NN-1);
  const int4* tk4 = (const int4*)(topk + n*KK);
  int idx[KK];
  #pragma unroll
  for (int q = 0; q < 5; q++){
    int4 v = tk4[q];
    idx[q*4+0]=v.x; idx[q*4+1]=v.y; idx[q*4+2]=v.z; idx[q*4+3]=v.w;
  }
  float siv = s_i[r];
  const float* sjb = s_j + b*NN;
  float xv[KK];
  #pragma unroll
  for (int k = 0; k < KK; k++){
    float x = siv + sjb[idx[k]];
    xv[k] = (x > 0.f) ? x : SLOPE * x;
  }
  float m = xv[0];
  #pragma unroll
  for (int k = 1; k < KK; k++) m = fmaxf(m, xv[k]);
  float ssum = 0.f;
  #pragma unroll
  for (int k = 0; k < KK; k++){ xv[k] = __expf(xv[k] - m); ssum += xv[k]; }
  float rinv = 1.f / ssum;
  float4* a4 = (float4*)(alpha + (size_t)r*KK);
  #pragma unroll
  for (int q = 0; q < 5; q++){
    float4 v = {xv[q*4+0]*rinv, xv[q*4+1]*rinv, xv[q*4+2]*rinv, xv[q*4+3]*rinv};
    a4[q] = v;
  }
}

// ------- kD: wave-per-row gather-FMA + BN1 stats -------------------------
// idx and alpha are wave-uniform scalar loads; only 20 coalesced 256B h-row
// gathers + 1 store on VMEM per row (softmax hoisted into kA2).
__global__ __launch_bounds__(256, 4)
void kD(const float* __restrict__ h, const float* __restrict__ alpha,
        const int* __restrict__ topk, const float* __restrict__ gnn_bias,
        float* __restrict__ outp, float* __restrict__ acc){
  __shared__ float sm[128];
  int t = threadIdx.x, wave = t >> 6, lane = t & 63;
  if (t < 128) sm[t] = 0.f;
  __syncthreads();
  int p = blockIdx.x;
  int xcd = p & 7, slot = p >> 3;
  int b = xcd + 8*(slot >> 6);               // 8 batches/XCD -> 2MB L2 set
  int chunk = slot & 63;
  const float* hb = h + (size_t)b * NN * DIM;
  float gb = gnn_bias[lane];
  float psum = 0.f, psq = 0.f;
  #pragma unroll 1
  for (int it2 = 0; it2 < 2; it2++){
    #pragma unroll
    for (int it = 0; it < 2; it++){
      int nu = __builtin_amdgcn_readfirstlane(chunk*16 + wave*4 + it2*2 + it);
      const float* arow = alpha + ((size_t)b*NN + nu)*KK;
      int idx[KK];
      #pragma unroll
      for (int k = 0; k < KK; k++)
        idx[k] = __builtin_amdgcn_readfirstlane(topk[nu*KK + k]);
      float g[KK];
      #pragma unroll
      for (int k = 0; k < KK; k++) g[k] = hb[idx[k]*DIM + lane];
      float o = 0.f;
      #pragma unroll
      for (int k = 0; k < KK; k++) o += arow[k] * g[k];
      o += gb;
      outp[((size_t)b*NN + nu)*DIM + lane] = o;
      psum += o; psq += o*o;
    }
  }
  atomicAdd(&sm[lane], psum);
  atomicAdd(&sm[64+lane], psq);
  __syncthreads();
  float* accr = acc + (p & (RD-1))*128;
  if (t < 128) atomicAdd(&accr[t], sm[t]);
}

// ------- kF: BN1 finalize (in-block) + BN2 stats over relu(bn1)*emb ------
__global__ void kF(const float* __restrict__ outp, const float* __restrict__ emb,
                   const float* __restrict__ acc, const float* __restrict__ bn1_g,
                   const float* __restrict__ bn1_b, float* __restrict__ acc2){
  __shared__ float prm[128];
  __shared__ float chs[DIM], chq[DIM];
  int t = threadIdx.x;
  if (t < DIM){ chs[t] = 0.f; chq[t] = 0.f; }
  if (t < 64){
    float smv = 0.f, sqv = 0.f;
    #pragma unroll
    for (int rp = 0; rp < RD; rp++){
      smv += acc[rp*128 + t];
      sqv += acc[rp*128 + 64 + t];
    }
    float mean = smv * (1.f / BN_COUNT);
    float var  = sqv * (1.f / BN_COUNT) - mean*mean;
    float sc = bn1_g[t] * rsqrtf(var + EPSV);
    prm[t]    = sc;
    prm[64+t] = bn1_b[t] - mean*sc;
  }
  __syncthreads();
  int cbase = (t*4) & 63;
  float4 sc = *(const float4*)(prm + cbase);
  float4 bs = *(const float4*)(prm + 64 + cbase);
  float s0=0,s1=0,s2=0,s3=0,q0=0,q1=0,q2=0,q3=0;
  const float4* op4 = (const float4*)outp;
  const float4* em4 = (const float4*)emb;
  const int total = BB*NN*DIM/4;
  for (int e = blockIdx.x*256 + t; e < total; e += 2048*256){
    float4 x = op4[e];
    float4 em = em4[e & (NN*DIM/4 - 1)];
    float4 y;
    y.x = fmaxf(x.x*sc.x + bs.x, 0.f) * em.x;
    y.y = fmaxf(x.y*sc.y + bs.y, 0.f) * em.y;
    y.z = fmaxf(x.z*sc.z + bs.z, 0.f) * em.z;
    y.w = fmaxf(x.w*sc.w + bs.w, 0.f) * em.w;
    s0 += y.x; q0 += y.x*y.x;
    s1 += y.y; q1 += y.y*y.y;
    s2 += y.z; q2 += y.z*y.z;
    s3 += y.w; q3 += y.w*y.w;
  }
  atomicAdd(&chs[cbase+0], s0); atomicAdd(&chq[cbase+0], q0);
  atomicAdd(&chs[cbase+1], s1); atomicAdd(&chq[cbase+1], q1);
  atomicAdd(&chs[cbase+2], s2); atomicAdd(&chq[cbase+2], q2);
  atomicAdd(&chs[cbase+3], s3); atomicAdd(&chq[cbase+3], q3);
  __syncthreads();
  float* acc2r = acc2 + (blockIdx.x & (RF-1))*128;
  if (t < 128) atomicAdd(&acc2r[t], (t < 64) ? chs[t] : chq[t-64]);
}

// ------- kH: finalize BN1+BN2 (in-block), recompute rep inline, dot ------
__global__ void kH(const float* __restrict__ outp, const float* __restrict__ emb,
                   const float* __restrict__ acc, const float* __restrict__ acc2,
                   const float* __restrict__ bn1_g, const float* __restrict__ bn1_b,
                   const float* __restrict__ bn2_g, const float* __restrict__ bn2_b,
                   const float* __restrict__ out_w, const float* __restrict__ out_b,
                   float* __restrict__ out){
  __shared__ float prm[256];
  int t = threadIdx.x, wave = t >> 6, lane = t & 63;
  if (t < 64){
    float smv = 0.f, sqv = 0.f;
    #pragma unroll
    for (int rp = 0; rp < RD; rp++){
      smv += acc[rp*128 + t];
      sqv += acc[rp*128 + 64 + t];
    }
    float mean = smv * (1.f / BN_COUNT);
    float var  = sqv * (1.f / BN_COUNT) - mean*mean;
    float sc = bn1_g[t] * rsqrtf(var + EPSV);
    prm[t]    = sc;
    prm[64+t] = bn1_b[t] - mean*sc;
  } else if (t < 128) {
    int d = t - 64;
    float smv = 0.f, sqv = 0.f;
    #pragma unroll
    for (int rp = 0; rp < RF; rp++){
      smv += acc2[rp*128 + d];
      sqv += acc2[rp*128 + 64 + d];
    }
    float mean = smv * (1.f / BN_COUNT);
    float var  = sqv * (1.f / BN_COUNT) - mean*mean;
    float sc = bn2_g[d] * rsqrtf(var + EPSV);
    prm[128+d] = sc;
    prm[192+d] = bn2_b[d] - mean*sc;
  }
  __syncthreads();
  int c16 = lane & 15, rsub = lane >> 4;
  int cb = c16*4;
  float4 sc1 = *(const float4*)(prm + cb);
  float4 bs1 = *(const float4*)(prm + 64 + cb);
  float4 sc2 = *(const float4*)(prm + 128 + cb);
  float4 bs2 = *(const float4*)(prm + 192 + cb);
  float4 w4 = *(const float4*)(out_w + cb);
  float ob = out_b[0];
  int rbase = blockIdx.x*64 + wave*16;
  #pragma unroll 1
  for (int i = 0; i < 16; i += 4){
    int r = rbase + i + rsub;
    int n = r & (NN-1);
    float4 x  = *(const float4*)(outp + (size_t)r*DIM + cb);
    float4 em = *(const float4*)(emb + n*DIM + cb);
    float4 y;
    y.x = fmaxf(x.x*sc1.x + bs1.x, 0.f) * em.x;
    y.y = fmaxf(x.y*sc1.y + bs1.y, 0.f) * em.y;
    y.z = fmaxf(x.z*sc1.z + bs1.z, 0.f) * em.z;
    y.w = fmaxf(x.w*sc1.w + bs1.w, 0.f) * em.w;
    float p = fmaxf(y.x*sc2.x + bs2.x, 0.f) * w4.x
            + fmaxf(y.y*sc2.y + bs2.y, 0.f) * w4.y
            + fmaxf(y.z*sc2.z + bs2.z, 0.f) * w4.z
            + fmaxf(y.w*sc2.w + bs2.w, 0.f) * w4.w;
    p += __shfl_xor(p, 1, 64); p += __shfl_xor(p, 2, 64);
    p += __shfl_xor(p, 4, 64); p += __shfl_xor(p, 8, 64);
    if (c16 == 0) out[r] = p + ob;
  }
}

extern "C" void kernel_launch(void* const* d_in, const int* in_sizes, int n_in,
                              void* d_out, int out_size, void* d_ws, size_t ws_size,
                              hipStream_t stream) {
  const float* data     = (const float*)d_in[0];
  const float* emb      = (const float*)d_in[2];
  const float* lin_w    = (const float*)d_in[3];
  const float* att_i    = (const float*)d_in[4];
  const float* att_j    = (const float*)d_in[5];
  const float* att_em_i = (const float*)d_in[6];
  const float* att_em_j = (const float*)d_in[7];
  const float* gnn_bias = (const float*)d_in[8];
  const float* bn1_g    = (const float*)d_in[9];
  const float* bn1_b    = (const float*)d_in[10];
  const float* bn2_g    = (const float*)d_in[11];
  const float* bn2_b    = (const float*)d_in[12];
  const float* out_w    = (const float*)d_in[13];
  const float* out_b    = (const float*)d_in[14];
  float* out = (float*)d_out;

  float* ws   = (float*)d_ws;
  float* h    = ws;                        // 4194304 floats
  float* outp = ws + 4194304;              // 4194304 (keys aliases first 1M)
  float* s_i  = ws + 8388608;              // 65536
  float* s_j  = s_i + 65536;               // 65536
  int*   topk = (int*)(s_j + 65536);       // 20480 ints
  float* acc1 = (float*)(topk + NN*KK);    // RD*128
  float* acc2 = acc1 + RD*128;             // RF*128
  float* prep = acc2 + RF*128;             // 32 + 2048
  float* alpha= prep + 32 + 2048;          // 65536*20 floats
  float* keys = outp;                      // dead before kD writes outp

  k1<<<256, 256, 0, stream>>>(emb, lin_w, att_i, att_j, att_em_i, att_em_j,
                              keys, prep, acc1);
  k2<<<128 + (BB*NN)/16, 256, 0, stream>>>(keys, data, lin_w, prep,
                                           topk, h, s_i, s_j);
  kA2<<<(BB*NN)/256, 256, 0, stream>>>(s_i, s_j, topk, alpha);
  kD<<<(BB*NN)/16, 256, 0, stream>>>(h, alpha, topk, gnn_bias, outp, acc1);
  kF<<<2048, 256, 0, stream>>>(outp, emb, acc1, bn1_g, bn1_b, acc2);
  kH<<<NN, 256, 0, stream>>>(outp, emb, acc1, acc2, bn1_g, bn1_b,
                             bn2_g, bn2_b, out_w, out_b, out);
}